// Round 7
// baseline (116.149 us; speedup 1.0000x reference)
//
#include <hip/hip_runtime.h>
#include <math.h>

#define TPB 256

typedef _Float16 f16x8 __attribute__((ext_vector_type(8)));
typedef float    f32x4 __attribute__((ext_vector_type(4)));

#define MFMA16(A, B, C) __builtin_amdgcn_mfma_f32_16x16x32_f16((A), (B), (C), 0, 0, 0)

// out = 0.25 * K^T * silu(K x K^T) * K per 64x64 image (math + chain verified R6, absmax 1.56e-2).
// R7 changes vs R6 (R6 was LDS-bank-conflict-bound: strides 36/68 dwords ≡ 4 mod 32 put all
// b128 frag reads on 8/32 banks -> 4x conflict, SQ_LDS_BANK_CONFLICT=4.55M):
//  (a) pad-free strides (64/128 cols) + XOR block swizzle:
//      addr(r,c) = r*S + (c&7) + (((c>>3) ^ (r&7)) << 3)   [16B blocks]
//      -> b128 reads and b64 writes both land uniformly on all 32 banks (minimum cycles).
//  (b) S4 stores D4 = 4*out directly to global in C/D layout (16 dword stores/wave,
//      4x64B contiguous segments each) -> buf4 + 2 barriers + 20 LDS ops removed.
//  (c) LDS 53760 -> 49664 B; 4 barriers/image.
// Chain (data-as-A alternating with data-as-B; zero explicit transposes — verified R6):
//   buf0 = x;  S1: D1 = x*K^T -> buf1 = D1^T;  S2: D2 = K*buf1^T = u, silu -> buf2 = S^T;
//   S3: D3 = buf2*K = S^T K -> buf3 = D3^T = K^T S;  S4: D4 = buf3*K = K^T S K = 4*out.

__device__ __forceinline__ int sw64(int r, int c) {   // u16 index, 64-col buffer
  return (r << 6) + (c & 7) + ((((c >> 3) ^ r) & 7) << 3);
}
__device__ __forceinline__ int sw128(int r, int c) {  // u16 index, 128-col buffer
  return (r << 7) + (c & 7) + ((((c >> 3) ^ (r & 7))) << 3);
}

__device__ __forceinline__ void store4h(_Float16* p, float a0, float a1, float a2, float a3) {
  float2 q;
  q.x = __builtin_bit_cast(float, __builtin_amdgcn_cvt_pkrtz(a0, a1));  // low half = a0
  q.y = __builtin_bit_cast(float, __builtin_amdgcn_cvt_pkrtz(a2, a3));
  *(float2*)p = q;  // ds_write_b64
}

__global__ __launch_bounds__(TPB, 3) void warped_mfma(const float* __restrict__ xin,
                                                      float* __restrict__ outp, int nimg) {
  __shared__ __attribute__((aligned(16))) _Float16 bufA[128 * 128];  // 32768 B
  __shared__ __attribute__((aligned(16))) _Float16 bufB[128 * 64];   // 16384 B
  __shared__ float k1d[128];

  _Float16* const buf0 = bufA;  // [64][64]   x, stage-in -> S1
  _Float16* const buf2 = bufA;  // [128][128] S^T, S2 -> S3
  _Float16* const buf1 = bufB;  // [128][64]  D1^T, S1 -> S2
  _Float16* const buf3 = bufB;  // [64][128]  K^T S, S3 -> S4

  const int tid = threadIdx.x;
  const int lane = tid & 63;
  const int w  = tid >> 6;  // wave 0..3
  const int wk = w >> 1;    // K-tile half (shared-frag axis)
  const int wd = w & 1;     // data-tile half
  const int lq = lane >> 4; // quad 0..3 (k dim of frags)
  const int ln = lane & 15; // m/n dim of frags

  // ---- 1D half-band kernel (verified R1): k(d) = (1/64)[1 + 2*sum cos(pi f d/64) + cos(pi d/2)]
  if (tid < 128) {
    const int d = tid;
    float s = 1.0f + ((d & 1) ? 0.0f : ((d & 2) ? -1.0f : 1.0f));
    for (int f = 1; f <= 31; ++f) {
      int r = (f * d) & 127;
      s += 2.0f * __cosf((float)r * 0.04908738521234052f /* pi/64 */);
    }
    k1d[d] = s * (1.0f / 64.0f);
  }
  __syncthreads();

  // ---- K fragments in registers (once per WG; verified R6)
  // AK[t][ks]: K[a][k], a=(wk*4+t)*16+ln, k=ks*32+lq*8+j.  S1 B-operand & S2 A-operand.
  f16x8 AK[4][2];
#pragma unroll
  for (int t = 0; t < 4; ++t)
#pragma unroll
    for (int ks = 0; ks < 2; ++ks) {
      const int a = (wk * 4 + t) * 16 + ln;
      f16x8 f;
#pragma unroll
      for (int j = 0; j < 8; ++j) {
        int k = ks * 32 + lq * 8 + j;
        f[j] = (_Float16)k1d[(a - 2 * k) & 127];
      }
      AK[t][ks] = f;
    }
  // BT[t][ks]: B[k][c] = K[k][c], c=(wk*2+t)*16+ln, k=ks*32+lq*8+j.  S3 & S4 B-operand.
  f16x8 BT[2][4];
#pragma unroll
  for (int t = 0; t < 2; ++t)
#pragma unroll
    for (int ks = 0; ks < 4; ++ks) {
      const int c = (wk * 2 + t) * 16 + ln;
      f16x8 f;
#pragma unroll
      for (int j = 0; j < 8; ++j) {
        int k = ks * 32 + lq * 8 + j;
        f[j] = (_Float16)k1d[(k - 2 * c) & 127];
      }
      BT[t][ks] = f;
    }

  const f32x4 vzero = {0.0f, 0.0f, 0.0f, 0.0f};

  for (int img = blockIdx.x; img < nimg; img += gridDim.x) {
    const float* __restrict__ x = xin + (size_t)img * 4096;
    float* __restrict__ out     = outp + (size_t)img * 4096;

    // ---- stage-in: buf0[i][j] = x[i][j] as f16 (coalesced float4 reads, packed b64 writes)
#pragma unroll
    for (int rep = 0; rep < 4; ++rep) {
      int idx = rep * 256 + tid;  // float4 index 0..1023
      float4 v = ((const float4*)x)[idx];
      int i = idx >> 4, j0 = (idx & 15) << 2;
      store4h(buf0 + sw64(i, j0), v.x, v.y, v.z, v.w);
    }
    __syncthreads();  // also orders prev image's S4 buf3 reads vs this S1's buf1 writes

    // ---- S1: D1 = x*K^T (64x128). m-tiles wd*2+{0,1}, n-tiles wk*4+{0..3}, ks 0..1.
    {
      f32x4 acc[2][4];
#pragma unroll
      for (int mtl = 0; mtl < 2; ++mtl)
#pragma unroll
        for (int ntl = 0; ntl < 4; ++ntl) acc[mtl][ntl] = vzero;
#pragma unroll
      for (int ks = 0; ks < 2; ++ks) {
        f16x8 Ad[2];
#pragma unroll
        for (int mtl = 0; mtl < 2; ++mtl)
          Ad[mtl] = *(const f16x8*)(buf0 + sw64((wd * 2 + mtl) * 16 + ln, ks * 32 + lq * 8));
#pragma unroll
        for (int mtl = 0; mtl < 2; ++mtl)
#pragma unroll
          for (int ntl = 0; ntl < 4; ++ntl)
            acc[mtl][ntl] = MFMA16(Ad[mtl], AK[ntl][ks], acc[mtl][ntl]);
      }
      // store D1^T: buf1[n][m] = D1[m][n]  (4 col-consecutive accs -> one b64)
#pragma unroll
      for (int mtl = 0; mtl < 2; ++mtl)
#pragma unroll
        for (int ntl = 0; ntl < 4; ++ntl) {
          int n0 = (wk * 4 + ntl) * 16, m0 = (wd * 2 + mtl) * 16;
          f32x4 a = acc[mtl][ntl];
          store4h(buf1 + sw64(n0 + ln, m0 + lq * 4), a[0], a[1], a[2], a[3]);
        }
    }
    __syncthreads();

    // ---- S2: D2 = K*buf1^T = u (128x128), silu. m-tiles wk*4+{0..3}, n-tiles wd*4+{0..3}
    //      (two n-passes of 2), ks 0..1. Writes buf2 over buf0 (dead since S1 barrier).
#pragma unroll
    for (int nh = 0; nh < 2; ++nh) {
      f32x4 acc[4][2];
#pragma unroll
      for (int mtl = 0; mtl < 4; ++mtl)
#pragma unroll
        for (int ntl = 0; ntl < 2; ++ntl) acc[mtl][ntl] = vzero;
#pragma unroll
      for (int ks = 0; ks < 2; ++ks) {
        f16x8 Bd[2];
#pragma unroll
        for (int ntl = 0; ntl < 2; ++ntl)
          Bd[ntl] = *(const f16x8*)(buf1 +
                                    sw64((wd * 4 + nh * 2 + ntl) * 16 + ln, ks * 32 + lq * 8));
#pragma unroll
        for (int mtl = 0; mtl < 4; ++mtl)
#pragma unroll
          for (int ntl = 0; ntl < 2; ++ntl)
            acc[mtl][ntl] = MFMA16(AK[mtl][ks], Bd[ntl], acc[mtl][ntl]);
      }
#pragma unroll
      for (int mtl = 0; mtl < 4; ++mtl)
#pragma unroll
        for (int ntl = 0; ntl < 2; ++ntl) {
          int n0 = (wd * 4 + nh * 2 + ntl) * 16, m0 = (wk * 4 + mtl) * 16;
          float s[4];
#pragma unroll
          for (int r = 0; r < 4; ++r) {
            float u = acc[mtl][ntl][r];
            s[r] = u * __builtin_amdgcn_rcpf(1.0f + __expf(-u));  // silu
          }
          store4h(buf2 + sw128(n0 + ln, m0 + lq * 4), s[0], s[1], s[2], s[3]);
        }
    }
    __syncthreads();

    // ---- S3: D3 = buf2*K = S^T K (128x64). m-tiles wd*4+{0..3}, n-tiles wk*2+{0,1}, ks 0..3.
    //      Writes buf3 over buf1 (dead since S2 barrier).
    {
      f32x4 acc[4][2];
#pragma unroll
      for (int mtl = 0; mtl < 4; ++mtl)
#pragma unroll
        for (int ntl = 0; ntl < 2; ++ntl) acc[mtl][ntl] = vzero;
#pragma unroll
      for (int ks = 0; ks < 4; ++ks) {
        f16x8 Ad[4];
#pragma unroll
        for (int mtl = 0; mtl < 4; ++mtl)
          Ad[mtl] = *(const f16x8*)(buf2 + sw128((wd * 4 + mtl) * 16 + ln, ks * 32 + lq * 8));
#pragma unroll
        for (int mtl = 0; mtl < 4; ++mtl)
#pragma unroll
          for (int ntl = 0; ntl < 2; ++ntl)
            acc[mtl][ntl] = MFMA16(Ad[mtl], BT[ntl][ks], acc[mtl][ntl]);
      }
#pragma unroll
      for (int mtl = 0; mtl < 4; ++mtl)
#pragma unroll
        for (int ntl = 0; ntl < 2; ++ntl) {
          int n0 = (wk * 2 + ntl) * 16, m0 = (wd * 4 + mtl) * 16;
          f32x4 a = acc[mtl][ntl];
          store4h(buf3 + sw128(n0 + ln, m0 + lq * 4), a[0], a[1], a[2], a[3]);
        }
    }
    __syncthreads();

    // ---- S4: D4 = buf3*K = 4*out (64x64). m-tiles wd*2+{0,1}, n-tiles wk*2+{0,1}, ks 0..3.
    //      Direct global store in C/D layout: out[m0+lq*4+r][n0+ln] (4x64B segments/store).
    {
      f32x4 acc[2][2];
#pragma unroll
      for (int mtl = 0; mtl < 2; ++mtl)
#pragma unroll
        for (int ntl = 0; ntl < 2; ++ntl) acc[mtl][ntl] = vzero;
#pragma unroll
      for (int ks = 0; ks < 4; ++ks) {
        f16x8 Ad[2];
#pragma unroll
        for (int mtl = 0; mtl < 2; ++mtl)
          Ad[mtl] = *(const f16x8*)(buf3 + sw128((wd * 2 + mtl) * 16 + ln, ks * 32 + lq * 8));
#pragma unroll
        for (int mtl = 0; mtl < 2; ++mtl)
#pragma unroll
          for (int ntl = 0; ntl < 2; ++ntl)
            acc[mtl][ntl] = MFMA16(Ad[mtl], BT[ntl][ks], acc[mtl][ntl]);
      }
#pragma unroll
      for (int mtl = 0; mtl < 2; ++mtl)
#pragma unroll
        for (int ntl = 0; ntl < 2; ++ntl) {
          int n0 = (wk * 2 + ntl) * 16, m0 = (wd * 2 + mtl) * 16;
#pragma unroll
          for (int r = 0; r < 4; ++r)
            out[(m0 + lq * 4 + r) * 64 + n0 + ln] = 0.25f * acc[mtl][ntl][r];
        }
    }
    // no barrier needed before next stage-in: it writes bufA (last read at S3, already
    // barriered); next stage-in's own barrier orders S4's buf3 reads vs S1's buf1 writes.
  }
}

extern "C" void kernel_launch(void* const* d_in, const int* in_sizes, int n_in,
                              void* d_out, int out_size, void* d_ws, size_t ws_size,
                              hipStream_t stream) {
  const float* x = (const float*)d_in[0];
  float* out = (float*)d_out;
  const int nimg = in_sizes[0] / 4096;  // B*C images of 64x64
  const int grid = (nimg + 1) / 2;      // 2 images per WG
  warped_mfma<<<dim3(grid), dim3(TPB), 0, stream>>>(x, out, nimg);
}